// Round 5
// baseline (492.626 us; speedup 1.0000x reference)
//
#include <hip/hip_runtime.h>

#define HH 1024
#define WW 1024
#define NBATCH 32
#define ROWS 16
#define NBINS 256
#define NSLOT 8
#define HSTRIDE 9   // bin stride (slot-padded): spreads random bins over all 32 banks

// searchsorted(bins, x, 'left') - 1 with bins[i] = i/256 (exact in fp32)
// == ceil(x*256) - 1:  x*256 exact (pow2 scale); noninteger t -> floor(t),
// integer t -> t-1 (left side), x==0 -> -1 (dropped). x<1 => bin <= 255.
__device__ inline int bin_of(float x) {
    return (int)ceilf(x * 256.0f) - 1;
}

__device__ inline float wave_red_f(float v) {
    #pragma unroll
    for (int off = 32; off > 0; off >>= 1) v += __shfl_down(v, off);
    return v;
}

__global__ __launch_bounds__(256, 8) void fused_main(
    const float* __restrict__ E, const float* __restrict__ O,
    unsigned int* __restrict__ gHistE, unsigned int* __restrict__ gHistO,
    double* __restrict__ sums)
{
    const int bt = blockIdx.y;
    const int r0 = blockIdx.x * ROWS;
    const float* __restrict__ e = E + (size_t)bt * HH * WW;
    const float* __restrict__ o = O + (size_t)bt * HH * WW;

    // block-shared, 8-slot replicated histograms, stride-9 bank padding
    __shared__ unsigned int hE[NBINS * HSTRIDE];
    __shared__ unsigned int hO[NBINS * HSTRIDE];
    __shared__ float rbuf[4][5];

    const int tid = threadIdx.x;
    #pragma unroll
    for (int i = 0; i < HSTRIDE; ++i) {
        hE[tid + i * 256] = 0u;
        hO[tid + i * 256] = 0u;
    }
    __syncthreads();

    const int lane = tid & 63;
    const int wv   = tid >> 6;
    const int slot = tid & (NSLOT - 1);
    const int c    = tid * 4;            // 256 threads cover 1024 cols, 4 each
    const bool edgeL    = (lane == 0);
    const bool edgeR    = (lane == 63);
    const bool hasRight = (c + 4 < WW);  // false only for the last quad

    auto loadrow = [&](const float* __restrict__ p, int r, float v[4]) {
        const float4 a = *reinterpret_cast<const float4*>(p + (size_t)r * WW + c);
        v[0] = a.x; v[1] = a.y; v[2] = a.z; v[3] = a.w;
    };

    // ---- software pipeline: rows r-1..r+1 resident, row r+3 in flight ----
    float prvE[4] = {0,0,0,0}, prvO[4] = {0,0,0,0};
    float curE[4], curO[4], nxtE[4], nxtO[4], p1E[4], p1O[4];
    if (r0 > 0) { loadrow(e, r0 - 1, prvE); loadrow(o, r0 - 1, prvO); }
    loadrow(e, r0,     curE); loadrow(o, r0,     curO);
    loadrow(e, r0 + 1, nxtE); loadrow(o, r0 + 1, nxtO);   // r0+1 <= 1009 < HH
    loadrow(e, r0 + 2, p1E);  loadrow(o, r0 + 2, p1O);    // r0+2 <= 1010 < HH

    // edge-lane horizontal neighbors for row r0 (pipelined 1 row ahead below)
    float lEc = 0.f, rEc = 0.f, lOc = 0.f, rOc = 0.f;
    if (edgeL && c > 0)    { lEc = e[(size_t)r0 * WW + c - 1]; lOc = o[(size_t)r0 * WW + c - 1]; }
    if (edgeR && hasRight) { rEc = e[(size_t)r0 * WW + c + 4]; rOc = o[(size_t)r0 * WW + c + 4]; }

    float accL1 = 0.f, accLapE = 0.f, accLapO = 0.f, accDx = 0.f, accDy = 0.f;

    #pragma unroll 4
    for (int k = 0; k < ROWS; ++k) {
        const int r = r0 + k;

        // 2-deep row prefetch: row r+3 (needed rows cap at r0+ROWS)
        float p2E[4], p2O[4];
        if (k + 3 <= ROWS && r + 3 < HH) {
            loadrow(e, r + 3, p2E); loadrow(o, r + 3, p2O);
        } else {
            #pragma unroll
            for (int j = 0; j < 4; ++j) { p2E[j] = 0.f; p2O[j] = 0.f; }
        }

        // 1-deep edge prefetch: row r+1's horizontal neighbors
        float lEn = 0.f, rEn = 0.f, lOn = 0.f, rOn = 0.f;
        if (k + 1 < ROWS) {
            const int rn = r + 1;
            if (edgeL && c > 0)    { lEn = e[(size_t)rn * WW + c - 1]; lOn = o[(size_t)rn * WW + c - 1]; }
            if (edgeR && hasRight) { rEn = e[(size_t)rn * WW + c + 4]; rOn = o[(size_t)rn * WW + c + 4]; }
        }

        // horizontal neighbors via intra-wave shuffles (cur is >=2 iters old)
        float lE = __shfl_up(curE[3], 1);
        float rE = __shfl_down(curE[0], 1);
        float lO = __shfl_up(curO[3], 1);
        float rO = __shfl_down(curO[0], 1);
        if (edgeL) { lE = lEc; lO = lOc; }   // c==0 -> 0 (zero pad)
        if (edgeR) { rE = rEc; rO = rOc; }   // no right -> 0

        #pragma unroll
        for (int j = 0; j < 4; ++j) {
            const float le = (j == 0) ? lE : curE[j-1];
            const float re = (j == 3) ? rE : curE[j+1];
            accLapE += fabsf(prvE[j] + nxtE[j] + le + re - 4.f * curE[j]);
            const float lo = (j == 0) ? lO : curO[j-1];
            const float ro = (j == 3) ? rO : curO[j+1];
            accLapO += fabsf(prvO[j] + nxtO[j] + lo + ro - 4.f * curO[j]);
            accL1 += fabsf(curE[j] - curO[j]);
            const int be = bin_of(curE[j]);
            if (be >= 0) atomicAdd(&hE[be * HSTRIDE + slot], 1u);
            const int bo = bin_of(curO[j]);
            if (bo >= 0) atomicAdd(&hO[bo * HSTRIDE + slot], 1u);
        }

        if (r + 1 < HH) {
            #pragma unroll
            for (int j = 0; j < 4; ++j) accDx += fabsf(nxtE[j] - curE[j]);
        }
        accDy += fabsf(curE[1]-curE[0]) + fabsf(curE[2]-curE[1]) + fabsf(curE[3]-curE[2]);
        if (hasRight) accDy += fabsf(rE - curE[3]);

        // rotate pipeline (renamed away by the unroll-4)
        #pragma unroll
        for (int j = 0; j < 4; ++j) {
            prvE[j] = curE[j]; curE[j] = nxtE[j]; nxtE[j] = p1E[j]; p1E[j] = p2E[j];
            prvO[j] = curO[j]; curO[j] = nxtO[j]; nxtO[j] = p1O[j]; p1O[j] = p2O[j];
        }
        lEc = lEn; rEc = rEn; lOc = lOn; rOc = rOn;
    }

    // block-reduce the 5 scalars; per-batch f64 atomics (32 blocks/address)
    float acc[5] = {accL1, accLapE, accLapO, accDx, accDy};
    #pragma unroll
    for (int kk = 0; kk < 5; ++kk) {
        const float w = wave_red_f(acc[kk]);
        if (lane == 0) rbuf[wv][kk] = w;
    }
    __syncthreads();
    if (tid == 0) {
        #pragma unroll
        for (int kk = 0; kk < 5; ++kk) {
            const double tot = (double)rbuf[0][kk] + rbuf[1][kk] + rbuf[2][kk] + rbuf[3][kk];
            atomicAdd(&sums[bt * 5 + kk], tot);
        }
    }

    // flush histograms: thread tid owns bin tid, folds its 8 slots
    unsigned int se = 0u, so = 0u;
    #pragma unroll
    for (int s = 0; s < NSLOT; ++s) {
        se += hE[tid * HSTRIDE + s];
        so += hO[tid * HSTRIDE + s];
    }
    atomicAdd(&gHistE[bt * NBINS + tid], se);
    atomicAdd(&gHistO[bt * NBINS + tid], so);
}

__global__ __launch_bounds__(256) void finalize(
    const unsigned int* __restrict__ gHistE, const unsigned int* __restrict__ gHistO,
    const double* __restrict__ sums, float* __restrict__ out)
{
    __shared__ double teL[NBATCH], toL[NBATCH];
    __shared__ double red[4];
    const int tid  = threadIdx.x;
    const int lane = tid & 63;
    const int wv   = tid >> 6;

    // phase 1: per-batch totals, one wave per 8 batches, no block syncs
    #pragma unroll
    for (int i = 0; i < NBATCH / 4; ++i) {
        const int bt = wv * (NBATCH / 4) + i;
        const uint4 a = *reinterpret_cast<const uint4*>(&gHistE[bt * NBINS + lane * 4]);
        const uint4 b = *reinterpret_cast<const uint4*>(&gHistO[bt * NBINS + lane * 4]);
        unsigned int te = a.x + a.y + a.z + a.w;
        unsigned int to = b.x + b.y + b.z + b.w;
        #pragma unroll
        for (int off = 32; off > 0; off >>= 1) {
            te += __shfl_down(te, off);
            to += __shfl_down(to, off);
        }
        if (lane == 0) { teL[bt] = (double)te; toL[bt] = (double)to; }
    }
    __syncthreads();

    // phase 2: thread owns bin=tid across all batches (loads are L2-hot)
    double hacc = 0.0;
    for (int bt = 0; bt < NBATCH; ++bt) {
        const double ce = (double)gHistE[bt * NBINS + tid];
        const double co = (double)gHistO[bt * NBINS + tid];
        const double he = (ce + 1e-6) / (teL[bt] + 1e-6);
        const double ho = (co + 1e-6) / (toL[bt] + 1e-6);
        const double d  = he - ho;
        hacc += d * d;
    }
    #pragma unroll
    for (int off = 32; off > 0; off >>= 1) hacc += __shfl_down(hacc, off);
    if (lane == 0) red[wv] = hacc;

    // wave 0 reduces the per-batch scalar sums meanwhile
    double s0 = 0, s1 = 0, s2 = 0, s3 = 0, s4 = 0;
    if (wv == 0) {
        if (lane < NBATCH) {
            s0 = sums[lane * 5 + 0]; s1 = sums[lane * 5 + 1]; s2 = sums[lane * 5 + 2];
            s3 = sums[lane * 5 + 3]; s4 = sums[lane * 5 + 4];
        }
        #pragma unroll
        for (int off = 32; off > 0; off >>= 1) {
            s0 += __shfl_down(s0, off); s1 += __shfl_down(s1, off);
            s2 += __shfl_down(s2, off); s3 += __shfl_down(s3, off);
            s4 += __shfl_down(s4, off);
        }
    }
    __syncthreads();

    if (tid == 0) {
        const double hsum = red[0] + red[1] + red[2] + red[3];
        const double hist = hsum / ((double)NBATCH * NBINS) / (double)NBINS;
        const double N    = (double)NBATCH * HH * WW;
        const double l1   = s0 / N;
        const double cE   = s1 / N;
        const double cO   = s2 / N;
        const double cont = fabs(cE - cO) / (cO + 1e-6);
        const double dxm  = s3 / ((double)NBATCH * (HH - 1) * WW);
        const double dym  = s4 / ((double)NBATCH * HH * (WW - 1));
        out[0] = (float)(l1 + 0.1 * hist + 0.1 * cont + 0.01 * (dxm + dym));
    }
}

extern "C" void kernel_launch(void* const* d_in, const int* in_sizes, int n_in,
                              void* d_out, int out_size, void* d_ws, size_t ws_size,
                              hipStream_t stream)
{
    const float* E = (const float*)d_in[0];  // enhanced_y
    const float* O = (const float*)d_in[1];  // original_y
    float* out = (float*)d_out;

    unsigned int* gHistE = (unsigned int*)d_ws;
    unsigned int* gHistO = gHistE + NBATCH * NBINS;
    double* sums = (double*)((char*)d_ws + (size_t)2 * NBATCH * NBINS * sizeof(unsigned int));

    // ws is poisoned 0xAA before every timed call -> zero the parts we use
    hipMemsetAsync(d_ws, 0,
                   (size_t)2 * NBATCH * NBINS * sizeof(unsigned int)
                   + (size_t)NBATCH * 5 * sizeof(double),
                   stream);

    dim3 grid(HH / ROWS, NBATCH);
    fused_main<<<grid, 256, 0, stream>>>(E, O, gHistE, gHistO, sums);
    finalize<<<1, 256, 0, stream>>>(gHistE, gHistO, sums, out);
}